// Round 1
// baseline (2954.338 us; speedup 1.0000x reference)
//
#include <hip/hip_runtime.h>

#define N_NODES 100000
#define N_EDGES 1600000
#define DIM 128

// ---------------- deg init: deg[i] = 2 (two self-loop concats) -------------
__global__ void k_init_deg(int* __restrict__ deg) {
    int i = blockIdx.x * 256 + threadIdx.x;
    if (i < N_NODES) deg[i] = 2;
}

// ---------------- deg count over destination (col) -------------------------
__global__ void k_count(const int* __restrict__ col, int* __restrict__ deg) {
    int e = blockIdx.x * 256 + threadIdx.x;
    if (e < N_EDGES) atomicAdd(&deg[col[e]], 1);
}

// ---------------- fused GEMM: xw = x@Wc ; acc = x@Wp + bp + bc + (2/deg)*xw
// block: 256 threads handles TM=64 nodes x 128 cols for BOTH weight matrices.
// thread (tx=tid&15, ty=tid>>4): cols tx*8..tx*8+7, nodes ty*4..ty*4+3.
#define TM 64
#define KB 16
__launch_bounds__(256)
__global__ void k_gemm(const float* __restrict__ x,
                       const float* __restrict__ Wc,
                       const float* __restrict__ Wp,
                       const float* __restrict__ bc,
                       const float* __restrict__ bp,
                       const int* __restrict__ deg,
                       float* __restrict__ xw,
                       float* __restrict__ acc) {
    __shared__ float xs[TM * 132];     // full 128-wide x rows, stride 132 (528B, 16B-aligned)
    __shared__ float wcs[KB * 128];
    __shared__ float wps[KB * 128];

    const int tid = threadIdx.x;
    const int tx = tid & 15;
    const int ty = tid >> 4;
    const int node0 = blockIdx.x * TM;

    // stage x tile: 64 rows x 32 float4
    #pragma unroll
    for (int i = tid; i < TM * 32; i += 256) {
        int r = i >> 5, c4 = i & 31;
        int node = node0 + r;
        float4 v = make_float4(0.f, 0.f, 0.f, 0.f);
        if (node < N_NODES) v = ((const float4*)x)[node * 32 + c4];
        *(float4*)(xs + r * 132 + c4 * 4) = v;
    }

    float accc[4][8], accp[4][8];
    #pragma unroll
    for (int r = 0; r < 4; r++)
        #pragma unroll
        for (int c = 0; c < 8; c++) { accc[r][c] = 0.f; accp[r][c] = 0.f; }

    for (int k0 = 0; k0 < DIM; k0 += KB) {
        __syncthreads();
        // stage W chunks: KB*32 float4 each
        #pragma unroll
        for (int i = tid; i < KB * 32; i += 256) {
            ((float4*)wcs)[i] = ((const float4*)Wc)[k0 * 32 + i];
            ((float4*)wps)[i] = ((const float4*)Wp)[k0 * 32 + i];
        }
        __syncthreads();

        #pragma unroll
        for (int kk = 0; kk < KB; kk += 4) {
            float4 av[4];
            #pragma unroll
            for (int r = 0; r < 4; r++)
                av[r] = *(const float4*)(xs + (ty * 4 + r) * 132 + k0 + kk);
            #pragma unroll
            for (int j = 0; j < 4; j++) {
                const float* wcrow = wcs + (kk + j) * 128 + tx * 8;
                const float* wprow = wps + (kk + j) * 128 + tx * 8;
                float4 wc0 = *(const float4*)(wcrow);
                float4 wc1 = *(const float4*)(wcrow + 4);
                float4 wp0 = *(const float4*)(wprow);
                float4 wp1 = *(const float4*)(wprow + 4);
                #pragma unroll
                for (int r = 0; r < 4; r++) {
                    float a = (j == 0) ? av[r].x : (j == 1) ? av[r].y
                            : (j == 2) ? av[r].z : av[r].w;
                    accc[r][0] += a * wc0.x; accc[r][1] += a * wc0.y;
                    accc[r][2] += a * wc0.z; accc[r][3] += a * wc0.w;
                    accc[r][4] += a * wc1.x; accc[r][5] += a * wc1.y;
                    accc[r][6] += a * wc1.z; accc[r][7] += a * wc1.w;
                    accp[r][0] += a * wp0.x; accp[r][1] += a * wp0.y;
                    accp[r][2] += a * wp0.z; accp[r][3] += a * wp0.w;
                    accp[r][4] += a * wp1.x; accp[r][5] += a * wp1.y;
                    accp[r][6] += a * wp1.z; accp[r][7] += a * wp1.w;
                }
            }
        }
    }

    // epilogue
    const int c0 = tx * 8;
    float4 bc0 = *(const float4*)(bc + c0);
    float4 bc1 = *(const float4*)(bc + c0 + 4);
    float4 bp0 = *(const float4*)(bp + c0);
    float4 bp1 = *(const float4*)(bp + c0 + 4);
    #pragma unroll
    for (int r = 0; r < 4; r++) {
        int node = node0 + ty * 4 + r;
        if (node >= N_NODES) continue;
        float sl = 2.0f / (float)deg[node];   // two self-loops, norm = dinv^2 each
        float4 o0 = make_float4(accc[r][0], accc[r][1], accc[r][2], accc[r][3]);
        float4 o1 = make_float4(accc[r][4], accc[r][5], accc[r][6], accc[r][7]);
        *(float4*)(xw + node * DIM + c0)     = o0;
        *(float4*)(xw + node * DIM + c0 + 4) = o1;
        float4 p0 = make_float4(accp[r][0] + bp0.x + bc0.x + sl * o0.x,
                                accp[r][1] + bp0.y + bc0.y + sl * o0.y,
                                accp[r][2] + bp0.z + bc0.z + sl * o0.z,
                                accp[r][3] + bp0.w + bc0.w + sl * o0.w);
        float4 p1 = make_float4(accp[r][4] + bp1.x + bc1.x + sl * o1.x,
                                accp[r][5] + bp1.y + bc1.y + sl * o1.y,
                                accp[r][6] + bp1.z + bc1.z + sl * o1.z,
                                accp[r][7] + bp1.w + bc1.w + sl * o1.w);
        *(float4*)(acc + node * DIM + c0)     = p0;
        *(float4*)(acc + node * DIM + c0 + 4) = p1;
    }
}

// ---------------- edge scatter: acc[col] += xw[row] * norm ------------------
// 32 threads per edge, float4 gather + 4 float atomics each.
__launch_bounds__(256)
__global__ void k_scatter(const int* __restrict__ row,
                          const int* __restrict__ col,
                          const int* __restrict__ deg,
                          const float* __restrict__ xw,
                          float* __restrict__ acc) {
    long long t = (long long)blockIdx.x * 256 + threadIdx.x;
    int e = (int)(t >> 5);
    int lane = (int)(t & 31);
    if (e >= N_EDGES) return;
    int r = row[e], c = col[e];
    float nrm = rsqrtf((float)deg[r]) * rsqrtf((float)deg[c]);
    float4 v = ((const float4*)(xw + (long long)r * DIM))[lane];
    float* dst = acc + (long long)c * DIM + lane * 4;
    atomicAdd(dst + 0, v.x * nrm);
    atomicAdd(dst + 1, v.y * nrm);
    atomicAdd(dst + 2, v.z * nrm);
    atomicAdd(dst + 3, v.w * nrm);
}

// ---------------- final: out = relu(acc) @ W_out + b_out --------------------
__launch_bounds__(256)
__global__ void k_final(const float* __restrict__ acc,
                        const float* __restrict__ wout,
                        const float* __restrict__ bout,
                        float* __restrict__ out) {
    int t = blockIdx.x * 256 + threadIdx.x;
    int node = t >> 6;
    int lane = t & 63;
    if (node >= N_NODES) return;
    float w0 = wout[lane], w1 = wout[lane + 64];
    float v0 = acc[node * DIM + lane], v1 = acc[node * DIM + lane + 64];
    float s = fmaxf(v0, 0.f) * w0 + fmaxf(v1, 0.f) * w1;
    #pragma unroll
    for (int off = 32; off > 0; off >>= 1) s += __shfl_down(s, off);
    if (lane == 0) out[node] = s + bout[0];
}

extern "C" void kernel_launch(void* const* d_in, const int* in_sizes, int n_in,
                              void* d_out, int out_size, void* d_ws, size_t ws_size,
                              hipStream_t stream) {
    const float* x      = (const float*)d_in[0];
    const int*   ei     = (const int*)  d_in[1];   // [2, E]: row then col
    const float* W_conv = (const float*)d_in[2];
    const float* b_conv = (const float*)d_in[3];
    const float* W_proj = (const float*)d_in[4];
    const float* b_proj = (const float*)d_in[5];
    const float* W_out  = (const float*)d_in[6];
    const float* b_out  = (const float*)d_in[7];
    float* out = (float*)d_out;

    const int* e_row = ei;
    const int* e_col = ei + N_EDGES;

    // workspace layout
    char* ws = (char*)d_ws;
    float* xw  = (float*)ws;                                   // N*128 f32 = 51.2 MB
    float* acc = (float*)(ws + (size_t)N_NODES * DIM * 4);     // N*128 f32 = 51.2 MB
    int*   deg = (int*)  (ws + (size_t)N_NODES * DIM * 8);     // N i32    = 0.4 MB

    k_init_deg<<<(N_NODES + 255) / 256, 256, 0, stream>>>(deg);
    k_count<<<(N_EDGES + 255) / 256, 256, 0, stream>>>(e_col, deg);
    k_gemm<<<(N_NODES + TM - 1) / TM, 256, 0, stream>>>(
        x, W_conv, W_proj, b_conv, b_proj, deg, xw, acc);
    k_scatter<<<(int)(((long long)N_EDGES * 32 + 255) / 256), 256, 0, stream>>>(
        e_row, e_col, deg, xw, acc);
    k_final<<<(N_NODES * 64 + 255) / 256, 256, 0, stream>>>(acc, W_out, b_out, out);
}

// Round 2
// 499.634 us; speedup vs baseline: 5.9130x; 5.9130x over previous
//
#include <hip/hip_runtime.h>

#define N_NODES 100000
#define N_EDGES 1600000
#define DIM 128

// ---- bf16 pack/unpack helpers ---------------------------------------------
__device__ inline unsigned pk_bf16(float a, float b) {
    unsigned ua = __builtin_bit_cast(unsigned, a);
    unsigned ub = __builtin_bit_cast(unsigned, b);
    ua = (ua + 0x7FFF + ((ua >> 16) & 1)) >> 16;          // RNE
    ub = (ub + 0x7FFF + ((ub >> 16) & 1)) >> 16;
    return ua | (ub << 16);
}
__device__ inline float bf16_lo(unsigned v) { return __builtin_bit_cast(float, v << 16); }
__device__ inline float bf16_hi(unsigned v) { return __builtin_bit_cast(float, v & 0xFFFF0000u); }

// ---------------- init: cnt = 0, counter = 0 -------------------------------
__global__ void k_init(int* __restrict__ cnt, int* __restrict__ counter) {
    int i = blockIdx.x * 256 + threadIdx.x;
    if (i < N_NODES) cnt[i] = 0;
    if (i == 0) counter[0] = 0;
}

// ---------------- in-degree count over destination (col) -------------------
__global__ void k_count(const int* __restrict__ col, int* __restrict__ cnt) {
    int e = blockIdx.x * 256 + threadIdx.x;
    if (e < N_EDGES) atomicAdd(&cnt[col[e]], 1);
}

// ---------------- bucket allocation: cursor[i] = region start; dinv --------
// Unordered CSR: per-block scan + one global atomic per block. Regions are
// disjoint+contiguous per node; global order is irrelevant.
__launch_bounds__(256)
__global__ void k_alloc(const int* __restrict__ cnt, int* __restrict__ cursor,
                        float* __restrict__ dinv, int* __restrict__ counter) {
    __shared__ int s[256];
    __shared__ int baseS;
    const int tid = threadIdx.x;
    const int i = blockIdx.x * 256 + tid;
    int c = (i < N_NODES) ? cnt[i] : 0;
    s[tid] = c;
    __syncthreads();
    #pragma unroll
    for (int off = 1; off < 256; off <<= 1) {
        int v = (tid >= off) ? s[tid - off] : 0;
        __syncthreads();
        s[tid] += v;
        __syncthreads();
    }
    if (tid == 255) baseS = atomicAdd(counter, s[255]);
    __syncthreads();
    if (i < N_NODES) {
        cursor[i] = baseS + s[tid] - c;                    // exclusive offset
        dinv[i] = rsqrtf((float)(c + 2));                  // deg = indeg + 2 self loops
    }
}

// ---------------- fill buckets: srcbuf[pos] = row --------------------------
__global__ void k_fill(const int* __restrict__ row, const int* __restrict__ col,
                       int* __restrict__ cursor, int* __restrict__ srcbuf) {
    int e = blockIdx.x * 256 + threadIdx.x;
    if (e < N_EDGES) {
        int pos = atomicAdd(&cursor[col[e]], 1);           // cursor ends at region end
        srcbuf[pos] = row[e];
    }
}

// ---------------- fused GEMM: xwb = bf16(x@Wc); acc = x@Wp+bp+bc+(2/deg)*xw
#define TM 64
#define KB 16
__launch_bounds__(256)
__global__ void k_gemm(const float* __restrict__ x,
                       const float* __restrict__ Wc,
                       const float* __restrict__ Wp,
                       const float* __restrict__ bc,
                       const float* __restrict__ bp,
                       const float* __restrict__ dinv,
                       unsigned* __restrict__ xwb,
                       float* __restrict__ acc) {
    __shared__ float xs[TM * 132];
    __shared__ float wcs[KB * 128];
    __shared__ float wps[KB * 128];

    const int tid = threadIdx.x;
    const int tx = tid & 15;
    const int ty = tid >> 4;
    const int node0 = blockIdx.x * TM;

    #pragma unroll
    for (int i = tid; i < TM * 32; i += 256) {
        int r = i >> 5, c4 = i & 31;
        int node = node0 + r;
        float4 v = make_float4(0.f, 0.f, 0.f, 0.f);
        if (node < N_NODES) v = ((const float4*)x)[node * 32 + c4];
        *(float4*)(xs + r * 132 + c4 * 4) = v;
    }

    float accc[4][8], accp[4][8];
    #pragma unroll
    for (int r = 0; r < 4; r++)
        #pragma unroll
        for (int c = 0; c < 8; c++) { accc[r][c] = 0.f; accp[r][c] = 0.f; }

    for (int k0 = 0; k0 < DIM; k0 += KB) {
        __syncthreads();
        #pragma unroll
        for (int i = tid; i < KB * 32; i += 256) {
            ((float4*)wcs)[i] = ((const float4*)Wc)[k0 * 32 + i];
            ((float4*)wps)[i] = ((const float4*)Wp)[k0 * 32 + i];
        }
        __syncthreads();

        #pragma unroll
        for (int kk = 0; kk < KB; kk += 4) {
            float4 av[4];
            #pragma unroll
            for (int r = 0; r < 4; r++)
                av[r] = *(const float4*)(xs + (ty * 4 + r) * 132 + k0 + kk);
            #pragma unroll
            for (int j = 0; j < 4; j++) {
                const float* wcrow = wcs + (kk + j) * 128 + tx * 8;
                const float* wprow = wps + (kk + j) * 128 + tx * 8;
                float4 wc0 = *(const float4*)(wcrow);
                float4 wc1 = *(const float4*)(wcrow + 4);
                float4 wp0 = *(const float4*)(wprow);
                float4 wp1 = *(const float4*)(wprow + 4);
                #pragma unroll
                for (int r = 0; r < 4; r++) {
                    float a = (j == 0) ? av[r].x : (j == 1) ? av[r].y
                            : (j == 2) ? av[r].z : av[r].w;
                    accc[r][0] += a * wc0.x; accc[r][1] += a * wc0.y;
                    accc[r][2] += a * wc0.z; accc[r][3] += a * wc0.w;
                    accc[r][4] += a * wc1.x; accc[r][5] += a * wc1.y;
                    accc[r][6] += a * wc1.z; accc[r][7] += a * wc1.w;
                    accp[r][0] += a * wp0.x; accp[r][1] += a * wp0.y;
                    accp[r][2] += a * wp0.z; accp[r][3] += a * wp0.w;
                    accp[r][4] += a * wp1.x; accp[r][5] += a * wp1.y;
                    accp[r][6] += a * wp1.z; accp[r][7] += a * wp1.w;
                }
            }
        }
    }

    const int c0 = tx * 8;
    float4 bc0 = *(const float4*)(bc + c0);
    float4 bc1 = *(const float4*)(bc + c0 + 4);
    float4 bp0 = *(const float4*)(bp + c0);
    float4 bp1 = *(const float4*)(bp + c0 + 4);
    #pragma unroll
    for (int r = 0; r < 4; r++) {
        int node = node0 + ty * 4 + r;
        if (node >= N_NODES) continue;
        float dv = dinv[node];
        float sl = 2.0f * dv * dv;                         // 2/deg: two self loops
        // bf16 xw store (4 packed uints = 16B)
        uint4 pk;
        pk.x = pk_bf16(accc[r][0], accc[r][1]);
        pk.y = pk_bf16(accc[r][2], accc[r][3]);
        pk.z = pk_bf16(accc[r][4], accc[r][5]);
        pk.w = pk_bf16(accc[r][6], accc[r][7]);
        *(uint4*)(xwb + node * 64 + tx * 4) = pk;
        float4 p0 = make_float4(accp[r][0] + bp0.x + bc0.x + sl * accc[r][0],
                                accp[r][1] + bp0.y + bc0.y + sl * accc[r][1],
                                accp[r][2] + bp0.z + bc0.z + sl * accc[r][2],
                                accp[r][3] + bp0.w + bc0.w + sl * accc[r][3]);
        float4 p1 = make_float4(accp[r][4] + bp1.x + bc1.x + sl * accc[r][4],
                                accp[r][5] + bp1.y + bc1.y + sl * accc[r][5],
                                accp[r][6] + bp1.z + bc1.z + sl * accc[r][6],
                                accp[r][7] + bp1.w + bc1.w + sl * accc[r][7]);
        *(float4*)(acc + node * DIM + c0)     = p0;
        *(float4*)(acc + node * DIM + c0 + 4) = p1;
    }
}

// ---------------- gather + relu + @W_out fused -----------------------------
// One 64-lane wave per node; lane handles features {2l, 2l+1}.
__launch_bounds__(256)
__global__ void k_gather_final(const int* __restrict__ srcbuf,
                               const int* __restrict__ cursor,
                               const int* __restrict__ cnt,
                               const float* __restrict__ dinv,
                               const unsigned* __restrict__ xwb,
                               const float* __restrict__ acc,
                               const float* __restrict__ wout,
                               const float* __restrict__ bout,
                               float* __restrict__ out) {
    int t = blockIdx.x * 256 + threadIdx.x;
    int node = t >> 6;
    int lane = t & 63;
    if (node >= N_NODES) return;

    int end = cursor[node];          // after k_fill, cursor = region end
    int c = cnt[node];
    int start = end - c;
    float ddst = dinv[node];

    float2 a = ((const float2*)acc)[node * 64 + lane];

    int j = start;
    for (; j + 1 < end; j += 2) {    // unroll-by-2 for memory-level parallelism
        int s0 = srcbuf[j], s1 = srcbuf[j + 1];
        unsigned v0 = xwb[s0 * 64 + lane];
        unsigned v1 = xwb[s1 * 64 + lane];
        float n0 = dinv[s0] * ddst;
        float n1 = dinv[s1] * ddst;
        a.x += bf16_lo(v0) * n0; a.y += bf16_hi(v0) * n0;
        a.x += bf16_lo(v1) * n1; a.y += bf16_hi(v1) * n1;
    }
    if (j < end) {
        int s0 = srcbuf[j];
        unsigned v0 = xwb[s0 * 64 + lane];
        float n0 = dinv[s0] * ddst;
        a.x += bf16_lo(v0) * n0; a.y += bf16_hi(v0) * n0;
    }

    float w0 = wout[2 * lane], w1 = wout[2 * lane + 1];
    float s = fmaxf(a.x, 0.f) * w0 + fmaxf(a.y, 0.f) * w1;
    #pragma unroll
    for (int off = 32; off > 0; off >>= 1) s += __shfl_down(s, off);
    if (lane == 0) out[node] = s + bout[0];
}

extern "C" void kernel_launch(void* const* d_in, const int* in_sizes, int n_in,
                              void* d_out, int out_size, void* d_ws, size_t ws_size,
                              hipStream_t stream) {
    const float* x      = (const float*)d_in[0];
    const int*   ei     = (const int*)  d_in[1];   // [2, E]: row then col
    const float* W_conv = (const float*)d_in[2];
    const float* b_conv = (const float*)d_in[3];
    const float* W_proj = (const float*)d_in[4];
    const float* b_proj = (const float*)d_in[5];
    const float* W_out  = (const float*)d_in[6];
    const float* b_out  = (const float*)d_in[7];
    float* out = (float*)d_out;

    const int* e_row = ei;
    const int* e_col = ei + N_EDGES;

    // workspace layout (~84.4 MB total)
    char* p = (char*)d_ws;
    unsigned* xwb  = (unsigned*)p; p += (size_t)N_NODES * 64 * 4;   // 25.6 MB
    float*    acc  = (float*)p;    p += (size_t)N_NODES * DIM * 4;  // 51.2 MB
    int*      cnt  = (int*)p;      p += (size_t)N_NODES * 4;        // 0.4 MB
    int*      cur  = (int*)p;      p += (size_t)N_NODES * 4;        // 0.4 MB
    float*    dinv = (float*)p;    p += (size_t)N_NODES * 4;        // 0.4 MB
    int*      srcb = (int*)p;      p += (size_t)N_EDGES * 4;        // 6.4 MB
    int*      ctr  = (int*)p;      p += 256;

    k_init <<<(N_NODES + 255) / 256, 256, 0, stream>>>(cnt, ctr);
    k_count<<<(N_EDGES + 255) / 256, 256, 0, stream>>>(e_col, cnt);
    k_alloc<<<(N_NODES + 255) / 256, 256, 0, stream>>>(cnt, cur, dinv, ctr);
    k_fill <<<(N_EDGES + 255) / 256, 256, 0, stream>>>(e_row, e_col, cur, srcb);
    k_gemm <<<(N_NODES + TM - 1) / TM, 256, 0, stream>>>(
        x, W_conv, W_proj, b_conv, b_proj, dinv, xwb, acc);
    k_gather_final<<<(N_NODES * 64 + 255) / 256, 256, 0, stream>>>(
        srcb, cur, cnt, dinv, xwb, acc, W_out, b_out, out);
}

// Round 3
// 346.581 us; speedup vs baseline: 8.5242x; 1.4416x over previous
//
#include <hip/hip_runtime.h>

#define N_NODES 100000
#define N_EDGES 1600000
#define DIM 128
#define CPAD 16          // one counter per 64B line
#define WT_STRIDE 136    // 128 + 8 bf16 pad: breaks LDS bank aliasing

typedef __attribute__((ext_vector_type(8))) short short8;
typedef __attribute__((ext_vector_type(4))) float f32x4;

// ---- bf16 helpers (RNE) ----------------------------------------------------
__device__ inline unsigned short bf16u(float f) {
    unsigned u = __builtin_bit_cast(unsigned, f);
    return (unsigned short)((u + 0x7FFFu + ((u >> 16) & 1u)) >> 16);
}
__device__ inline unsigned pk_bf16(float a, float b) {
    return (unsigned)bf16u(a) | ((unsigned)bf16u(b) << 16);
}
__device__ inline float bf16_lo(unsigned v) { return __builtin_bit_cast(float, v << 16); }
__device__ inline float bf16_hi(unsigned v) { return __builtin_bit_cast(float, v & 0xFFFF0000u); }

// ---------------- init: zero padded counters + global cursor ---------------
__global__ void k_init(int* __restrict__ cntp, int* __restrict__ ctr) {
    int i = blockIdx.x * 256 + threadIdx.x;
    if (i < N_NODES * CPAD) cntp[i] = 0;
    if (i == 0) *ctr = 0;
}

// ---------------- count + rank in ONE atomic pass --------------------------
__global__ void k_rank(const int* __restrict__ col, int* __restrict__ cntp,
                       int* __restrict__ rank) {
    int e = blockIdx.x * 256 + threadIdx.x;
    if (e < N_EDGES) rank[e] = atomicAdd(&cntp[col[e] * CPAD], 1);
}

// ---------------- region starts via block scan + global cursor -------------
__launch_bounds__(256)
__global__ void k_alloc(const int* __restrict__ cntp, int* __restrict__ start,
                        int* __restrict__ ccnt, float* __restrict__ dinv,
                        int* __restrict__ ctr) {
    __shared__ int s[256];
    __shared__ int baseS;
    const int tid = threadIdx.x;
    const int i = blockIdx.x * 256 + tid;
    int c = (i < N_NODES) ? cntp[i * CPAD] : 0;
    s[tid] = c;
    __syncthreads();
    #pragma unroll
    for (int off = 1; off < 256; off <<= 1) {
        int v = (tid >= off) ? s[tid - off] : 0;
        __syncthreads();
        s[tid] += v;
        __syncthreads();
    }
    if (tid == 255) baseS = atomicAdd(ctr, s[255]);
    __syncthreads();
    if (i < N_NODES) {
        start[i] = baseS + s[tid] - c;
        ccnt[i]  = c;
        dinv[i]  = rsqrtf((float)(c + 2));   // deg = indeg + 2 self loops
    }
}

// ---------------- atomic-free bucket fill ----------------------------------
__global__ void k_scatter_src(const int* __restrict__ row, const int* __restrict__ col,
                              const int* __restrict__ rank, const int* __restrict__ start,
                              int* __restrict__ srcb) {
    int e = blockIdx.x * 256 + threadIdx.x;
    if (e < N_EDGES) srcb[start[col[e]] + rank[e]] = row[e];
}

// ---------------- MFMA GEMM: xwb = bf16(x@Wc); acc = x@Wp+bp+bc+(2/deg)*xw -
// Block: 256 threads (4 waves) = 64 nodes x 256 cols ([Wc|Wp]).
// Wave w: rows w*16..w*16+15, 16 col-tiles of 16, K=128 in 4 steps of 32.
__launch_bounds__(256)
__global__ void k_gemm(const float* __restrict__ x,
                       const float* __restrict__ Wc,
                       const float* __restrict__ Wp,
                       const float* __restrict__ bc,
                       const float* __restrict__ bp,
                       const float* __restrict__ dinv,
                       unsigned* __restrict__ xwb,
                       float* __restrict__ acc) {
    __shared__ __align__(16) unsigned short Wt[256 * WT_STRIDE]; // 69632 B
    float* Ds = (float*)Wt;                                      // reused post K-loop

    const int tid = threadIdx.x;
    const int node0 = blockIdx.x * 64;

    // stage Wt[n][k] = bf16(W[k][n]); n<128: Wc, n>=128: Wp. Coalesced float4 reads.
    for (int i = tid; i < 2 * 128 * 32; i += 256) {
        int half = i >> 12;
        int r = (i >> 5) & 127;   // k
        int q = i & 31;           // float4 within row
        float4 w = half ? ((const float4*)Wp)[r * 32 + q]
                        : ((const float4*)Wc)[r * 32 + q];
        int nb = half * 128 + q * 4;
        Wt[(nb + 0) * WT_STRIDE + r] = bf16u(w.x);
        Wt[(nb + 1) * WT_STRIDE + r] = bf16u(w.y);
        Wt[(nb + 2) * WT_STRIDE + r] = bf16u(w.z);
        Wt[(nb + 3) * WT_STRIDE + r] = bf16u(w.w);
    }
    __syncthreads();

    const int w    = tid >> 6;
    const int lane = tid & 63;
    const int m    = lane & 15;
    const int quad = lane >> 4;

    const int  rowg  = node0 + w * 16 + m;
    const bool valid = rowg < N_NODES;
    const float* xrow = x + (size_t)rowg * DIM;

    f32x4 accf[16];
    #pragma unroll
    for (int t = 0; t < 16; t++) accf[t] = (f32x4){0.f, 0.f, 0.f, 0.f};

    #pragma unroll
    for (int q = 0; q < 4; q++) {
        // A frag: A[m][k], k = 32q + 8*quad + j (j=0..7)
        float4 xa = make_float4(0.f, 0.f, 0.f, 0.f);
        float4 xb = make_float4(0.f, 0.f, 0.f, 0.f);
        if (valid) {
            xa = *(const float4*)(xrow + 32 * q + 8 * quad);
            xb = *(const float4*)(xrow + 32 * q + 8 * quad + 4);
        }
        uint4 pa;
        pa.x = pk_bf16(xa.x, xa.y); pa.y = pk_bf16(xa.z, xa.w);
        pa.z = pk_bf16(xb.x, xb.y); pa.w = pk_bf16(xb.z, xb.w);
        short8 afrag = __builtin_bit_cast(short8, pa);
        #pragma unroll
        for (int t = 0; t < 16; t++) {
            // B frag: B[k][n], n = 16t + m, k = 32q + 8*quad + j — 16B contiguous
            const unsigned short* bptr = Wt + (t * 16 + m) * WT_STRIDE + 32 * q + 8 * quad;
            short8 bfrag = *(const short8*)bptr;
            accf[t] = __builtin_amdgcn_mfma_f32_16x16x32_bf16(afrag, bfrag, accf[t], 0, 0, 0);
        }
    }

    // D -> LDS (row-major, stride 260) for coalesced global stores
    __syncthreads();   // all waves done reading Wt
    #pragma unroll
    for (int t = 0; t < 16; t++)
        #pragma unroll
        for (int r = 0; r < 4; r++)
            Ds[(w * 16 + quad * 4 + r) * 260 + t * 16 + m] = accf[t][r];
    __syncthreads();

    // epilogue: thread -> (row = tid>>2, q4 = tid&3), float4 cols q4*4 + 16j
    const int rowL = tid >> 2, q4 = tid & 3;
    const int node = node0 + rowL;
    if (node < N_NODES) {
        float dv = dinv[node];
        float sl = 2.0f * dv * dv;           // two self loops: 2/deg
        const float* dsr = Ds + rowL * 260;
        #pragma unroll
        for (int j = 0; j < 8; j++) {
            int c = q4 * 4 + 16 * j;
            float4 xw4 = *(const float4*)(dsr + c);
            float4 pr4 = *(const float4*)(dsr + 128 + c);
            float4 bc4 = *(const float4*)(bc + c);
            float4 bp4 = *(const float4*)(bp + c);
            float4 o;
            o.x = pr4.x + bp4.x + bc4.x + sl * xw4.x;
            o.y = pr4.y + bp4.y + bc4.y + sl * xw4.y;
            o.z = pr4.z + bp4.z + bc4.z + sl * xw4.z;
            o.w = pr4.w + bp4.w + bc4.w + sl * xw4.w;
            *(float4*)(acc + (size_t)node * DIM + c) = o;
            uint2 pk2;
            pk2.x = pk_bf16(xw4.x, xw4.y);
            pk2.y = pk_bf16(xw4.z, xw4.w);
            *(uint2*)(xwb + (size_t)node * 64 + (c >> 1)) = pk2;
        }
    }
}

// ---------------- gather + relu + @W_out fused (wave per node) -------------
__launch_bounds__(256)
__global__ void k_gather_final(const int* __restrict__ srcb,
                               const int* __restrict__ start,
                               const int* __restrict__ ccnt,
                               const float* __restrict__ dinv,
                               const unsigned* __restrict__ xwb,
                               const float* __restrict__ acc,
                               const float* __restrict__ wout,
                               const float* __restrict__ bout,
                               float* __restrict__ out) {
    int t = blockIdx.x * 256 + threadIdx.x;
    int node = t >> 6;
    int lane = t & 63;
    if (node >= N_NODES) return;

    int s0  = start[node];
    int end = s0 + ccnt[node];
    float ddst = dinv[node];

    float2 a = ((const float2*)acc)[node * 64 + lane];

    int j = s0;
    for (; j + 3 < end; j += 4) {
        int r0 = srcb[j], r1 = srcb[j + 1], r2 = srcb[j + 2], r3 = srcb[j + 3];
        unsigned v0 = xwb[r0 * 64 + lane], v1 = xwb[r1 * 64 + lane];
        unsigned v2 = xwb[r2 * 64 + lane], v3 = xwb[r3 * 64 + lane];
        float n0 = dinv[r0] * ddst, n1 = dinv[r1] * ddst;
        float n2 = dinv[r2] * ddst, n3 = dinv[r3] * ddst;
        a.x += bf16_lo(v0) * n0 + bf16_lo(v1) * n1 + bf16_lo(v2) * n2 + bf16_lo(v3) * n3;
        a.y += bf16_hi(v0) * n0 + bf16_hi(v1) * n1 + bf16_hi(v2) * n2 + bf16_hi(v3) * n3;
    }
    for (; j < end; j++) {
        int r0 = srcb[j];
        unsigned v0 = xwb[r0 * 64 + lane];
        float n0 = dinv[r0] * ddst;
        a.x += bf16_lo(v0) * n0;
        a.y += bf16_hi(v0) * n0;
    }

    float w0 = wout[2 * lane], w1 = wout[2 * lane + 1];
    float s = fmaxf(a.x, 0.f) * w0 + fmaxf(a.y, 0.f) * w1;
    #pragma unroll
    for (int off = 32; off > 0; off >>= 1) s += __shfl_down(s, off);
    if (lane == 0) out[node] = s + bout[0];
}

extern "C" void kernel_launch(void* const* d_in, const int* in_sizes, int n_in,
                              void* d_out, int out_size, void* d_ws, size_t ws_size,
                              hipStream_t stream) {
    const float* x      = (const float*)d_in[0];
    const int*   ei     = (const int*)  d_in[1];   // [2, E]: row then col
    const float* W_conv = (const float*)d_in[2];
    const float* b_conv = (const float*)d_in[3];
    const float* W_proj = (const float*)d_in[4];
    const float* b_proj = (const float*)d_in[5];
    const float* W_out  = (const float*)d_in[6];
    const float* b_out  = (const float*)d_in[7];
    float* out = (float*)d_out;

    const int* e_row = ei;
    const int* e_col = ei + N_EDGES;

    // workspace layout (~97.2 MB)
    char* p = (char*)d_ws;
    unsigned* xwb   = (unsigned*)p; p += (size_t)N_NODES * 64 * 4;    // 25.6 MB
    float*    acc   = (float*)p;    p += (size_t)N_NODES * DIM * 4;   // 51.2 MB
    int*      cntp  = (int*)p;      p += (size_t)N_NODES * CPAD * 4;  // 6.4 MB
    int*      start = (int*)p;      p += (size_t)N_NODES * 4;         // 0.4 MB
    int*      ccnt  = (int*)p;      p += (size_t)N_NODES * 4;         // 0.4 MB
    float*    dinv  = (float*)p;    p += (size_t)N_NODES * 4;         // 0.4 MB
    int*      rank  = (int*)p;      p += (size_t)N_EDGES * 4;         // 6.4 MB
    int*      srcb  = (int*)p;      p += (size_t)N_EDGES * 4;         // 6.4 MB
    int*      ctr   = (int*)p;      p += 256;

    k_init<<<(N_NODES * CPAD + 255) / 256, 256, 0, stream>>>(cntp, ctr);
    k_rank<<<(N_EDGES + 255) / 256, 256, 0, stream>>>(e_col, cntp, rank);
    k_alloc<<<(N_NODES + 255) / 256, 256, 0, stream>>>(cntp, start, ccnt, dinv, ctr);
    k_scatter_src<<<(N_EDGES + 255) / 256, 256, 0, stream>>>(e_row, e_col, rank, start, srcb);
    k_gemm<<<(N_NODES + 63) / 64, 256, 0, stream>>>(
        x, W_conv, W_proj, b_conv, b_proj, dinv, xwb, acc);
    k_gather_final<<<(N_NODES * 64 + 255) / 256, 256, 0, stream>>>(
        srcb, start, ccnt, dinv, xwb, acc, W_out, b_out, out);
}